// Round 3
// baseline (227.462 us; speedup 1.0000x reference)
//
#include <hip/hip_runtime.h>
#include <stdint.h>

#define B_TOT 16384
#define F_NUM 24
#define D_DIM 64
#define P_NUM 276
#define BT    64          // b-columns per block (2 MFMA n-subtiles)
#define NTH   512
#define ROWS  770         // shorts per LDS row: 768 + 2 pad -> 385 words (odd: conflict-free)

typedef float f32x16 __attribute__((ext_vector_type(16)));
typedef short bf16x8 __attribute__((ext_vector_type(8)));

__device__ inline unsigned short f2bf(float f) {
    unsigned u = __float_as_uint(f);
    u += 0x7fffu + ((u >> 16) & 1u);      // round-to-nearest-even
    return (unsigned short)(u >> 16);
}

// ---------------- pair schedule: fields partitioned across 8 waves ----------
// counts per wave: {34,34,34,34,34,34,36,36}; every field group ends with j==23
struct WTab { int ent[8][36]; };
constexpr WTab build_tab() {
    WTab t{};
    const int fl[8][6] = {
        {0,12,-1,-1,-1,-1},
        {1,11,-1,-1,-1,-1},
        {2,10,-1,-1,-1,-1},
        {3, 9,-1,-1,-1,-1},
        {4, 8,-1,-1,-1,-1},
        {5, 7,-1,-1,-1,-1},
        {6,14,17,20,22,-1},
        {13,15,16,18,19,21}};
    for (int w = 0; w < 8; ++w) {
        int c = 0;
        for (int k = 0; k < 6; ++k) {
            int f = fl[w][k];
            if (f < 0) break;
            int base = 23 * f - f * (f - 1) / 2;      // p of pair (f, f+1)
            for (int j = f + 1; j < 24; ++j)
                t.ent[w][c++] = (base + j - f - 1) | (j << 9) | (f << 14);
        }
        int last = t.ent[w][c - 1];
        while (c < 36) t.ent[w][c++] = last;          // pad (never executed)
    }
    return t;
}
__device__ __constant__ WTab gtab = build_tab();

// ---------------- prepass: W fp32 -> bf16 A-fragments, ks-major layout ------
// chunk(ks, p, m) = 64 lanes x 8 shorts at afrag[(((ks*P + p)*2 + m)*64 + lane)*8]
//   elem i = W[p][m*32 + (lane&31)][ks*16 + (lane>>5)*8 + i]
__global__ __launch_bounds__(256) void wprep(const float* __restrict__ W,
                                             unsigned short* __restrict__ afrag) {
    __shared__ __align__(16) unsigned short wlds[64 * 72];
    int p = blockIdx.x, t = threadIdx.x;
    const float4* src = (const float4*)(W + (size_t)p * 4096);
    #pragma unroll
    for (int c = 0; c < 4; ++c) {
        int i = t + c * 256;             // float4 index 0..1023 (coalesced)
        float4 v = src[i];
        int d = i >> 4;
        int e = (i & 15) * 4;
        ushort4 h; h.x=f2bf(v.x); h.y=f2bf(v.y); h.z=f2bf(v.z); h.w=f2bf(v.w);
        *(ushort4*)(&wlds[d * 72 + e]) = h;
    }
    __syncthreads();
    #pragma unroll
    for (int c = 0; c < 2; ++c) {
        int sl = t + c * 256;            // 0..511
        int u = sl >> 6, lane = sl & 63;
        int ks = u >> 1, m = u & 1;
        int d = m * 32 + (lane & 31);
        int e = ks * 16 + (lane >> 5) * 8;
        bf16x8 v = *(const bf16x8*)(&wlds[d * 72 + e]);
        size_t dst = ((size_t)((ks * P_NUM + p) * 2 + m) * 64 + lane) * 8;
        *(bf16x8*)(afrag + dst) = v;     // 1KB contiguous per 64-lane group
    }
}

// ---------------- main kernel: BT=64, 2 K-phases of e-half ------------------
__global__ __launch_bounds__(NTH, 2) void fmfm_main(const float* __restrict__ x,
                                                    const unsigned short* __restrict__ afrag,
                                                    float* __restrict__ out) {
    __shared__ __align__(16) unsigned short xs[BT * ROWS];   // 98,560 B
    __shared__ float t_red[BT];
    const int tid = threadIdx.x;
    const int btile = blockIdx.x;
    const int lane = tid & 63;
    const int wv = __builtin_amdgcn_readfirstlane(tid >> 6);
    const int bcol = lane & 31;
    const int q = lane >> 5;

    if (tid < BT) t_red[tid] = 0.0f;

    const int cnt = (wv < 6) ? 34 : 36;
    const bf16x8* afr = (const bf16x8*)afrag;

    float tacc0 = 0.0f, tacc1 = 0.0f;
    f32x16 acc00, acc01, acc10, acc11;      // [n][m]
    #pragma unroll
    for (int i = 0; i < 16; ++i) { acc00[i]=0.f; acc01[i]=0.f; acc10[i]=0.f; acc11[i]=0.f; }

    const float* xg  = x + (size_t)btile * BT * 1536;
    const float* xe0 = xg + (size_t)bcol * 1536 + 4 * q;     // epilogue base, n=0
    const float* xe1 = xe0 + (size_t)32 * 1536;              // n=1
    const unsigned short* xr0 = xs + bcol * ROWS;
    const unsigned short* xr1 = xs + (bcol + 32) * ROWS;

    for (int h = 0; h < 2; ++h) {
        __syncthreads();    // protect LDS from previous phase's readers
        // ---- stage e-half h: 64 rows x 24 fields x 32 e, fp32 -> bf16 ----
        for (int k = 0; k < 24; ++k) {
            int g = tid + k * NTH;           // 0..12287
            int row = g / 192;
            int r = g - row * 192;
            int f = r >> 3, i = r & 7;
            float4 v = *(const float4*)(xg + (size_t)row * 1536 + f * 64 + h * 32 + i * 4);
            ushort4 hh; hh.x=f2bf(v.x); hh.y=f2bf(v.y); hh.z=f2bf(v.z); hh.w=f2bf(v.w);
            *(ushort4*)(&xs[row * ROWS + f * 32 + i * 4]) = hh;
        }
        __syncthreads();

        const int ks0 = 2 * h;

        auto epi = [&](int f) {              // partial epilogue (linear in V)
            const float* e0 = xe0 + f * 64;
            const float* e1 = xe1 + f * 64;
            #pragma unroll
            for (int g = 0; g < 4; ++g) {
                float4 v = *(const float4*)(e0 + 8 * g);
                tacc0 += acc00[4*g+0]*v.x + acc00[4*g+1]*v.y + acc00[4*g+2]*v.z + acc00[4*g+3]*v.w;
                v = *(const float4*)(e0 + 32 + 8 * g);
                tacc0 += acc01[4*g+0]*v.x + acc01[4*g+1]*v.y + acc01[4*g+2]*v.z + acc01[4*g+3]*v.w;
                v = *(const float4*)(e1 + 8 * g);
                tacc1 += acc10[4*g+0]*v.x + acc10[4*g+1]*v.y + acc10[4*g+2]*v.z + acc10[4*g+3]*v.w;
                v = *(const float4*)(e1 + 32 + 8 * g);
                tacc1 += acc11[4*g+0]*v.x + acc11[4*g+1]*v.y + acc11[4*g+2]*v.z + acc11[4*g+3]*v.w;
            }
            #pragma unroll
            for (int i = 0; i < 16; ++i) { acc00[i]=0.f; acc01[i]=0.f; acc10[i]=0.f; acc11[i]=0.f; }
        };

        // one step: 4 LDS b-frags, 8 MFMAs (4 chains x 2), depth-2 W prefetch
        auto step = [&](int s, bf16x8* buf) {
            int e = gtab.ent[wv][s];
            int j = (e >> 9) & 31;
            int f = e >> 14;
            const unsigned short* a0 = xr0 + j * 32 + q * 8;
            const unsigned short* a1 = xr1 + j * 32 + q * 8;
            bf16x8 b00 = *(const bf16x8*)(a0);         // n=0, ksl=0
            bf16x8 b01 = *(const bf16x8*)(a0 + 16);    // n=0, ksl=1
            bf16x8 b10 = *(const bf16x8*)(a1);
            bf16x8 b11 = *(const bf16x8*)(a1 + 16);
            acc00 = __builtin_amdgcn_mfma_f32_32x32x16_bf16(buf[0], b00, acc00, 0, 0, 0);
            acc01 = __builtin_amdgcn_mfma_f32_32x32x16_bf16(buf[1], b00, acc01, 0, 0, 0);
            acc10 = __builtin_amdgcn_mfma_f32_32x32x16_bf16(buf[0], b10, acc10, 0, 0, 0);
            acc11 = __builtin_amdgcn_mfma_f32_32x32x16_bf16(buf[1], b10, acc11, 0, 0, 0);
            acc00 = __builtin_amdgcn_mfma_f32_32x32x16_bf16(buf[2], b01, acc00, 0, 0, 0);
            acc01 = __builtin_amdgcn_mfma_f32_32x32x16_bf16(buf[3], b01, acc01, 0, 0, 0);
            acc10 = __builtin_amdgcn_mfma_f32_32x32x16_bf16(buf[2], b11, acc10, 0, 0, 0);
            acc11 = __builtin_amdgcn_mfma_f32_32x32x16_bf16(buf[3], b11, acc11, 0, 0, 0);
            int sp = (s + 2 < cnt) ? s + 2 : cnt - 1;
            int pp = gtab.ent[wv][sp] & 511;
            #pragma unroll
            for (int u = 0; u < 4; ++u) {
                int ksl = u >> 1, m = u & 1;
                buf[u] = afr[(size_t)(((ks0 + ksl) * P_NUM + pp) * 2 + m) * 64 + lane];
            }
            if (j == 23) epi(f);             // wave-uniform branch
        };

        bf16x8 bufA[4], bufB[4];
        {
            int p0 = gtab.ent[wv][0] & 511;
            #pragma unroll
            for (int u = 0; u < 4; ++u) {
                int ksl = u >> 1, m = u & 1;
                bufA[u] = afr[(size_t)(((ks0 + ksl) * P_NUM + p0) * 2 + m) * 64 + lane];
            }
            int p1 = gtab.ent[wv][1] & 511;
            #pragma unroll
            for (int u = 0; u < 4; ++u) {
                int ksl = u >> 1, m = u & 1;
                bufB[u] = afr[(size_t)(((ks0 + ksl) * P_NUM + p1) * 2 + m) * 64 + lane];
            }
        }
        for (int s = 0; s < cnt; s += 2) {   // ping-pong, no register rotation
            step(s,     bufA);
            step(s + 1, bufB);
        }
    }

    atomicAdd(&t_red[bcol],      tacc0);
    atomicAdd(&t_red[bcol + 32], tacc1);
    __syncthreads();
    if (tid < BT) out[(size_t)btile * BT + tid] = t_red[tid];
}

extern "C" void kernel_launch(void* const* d_in, const int* in_sizes, int n_in,
                              void* d_out, int out_size, void* d_ws, size_t ws_size,
                              hipStream_t stream) {
    const float* x = (const float*)d_in[0];
    const float* W = (const float*)d_in[1];
    float* out = (float*)d_out;
    unsigned short* afrag = (unsigned short*)d_ws;   // 2.26 MB scratch
    wprep<<<P_NUM, 256, 0, stream>>>(W, afrag);
    fmfm_main<<<B_TOT / BT, NTH, 0, stream>>>(x, afrag, out);
}

// Round 4
// 225.855 us; speedup vs baseline: 1.0071x; 1.0071x over previous
//
#include <hip/hip_runtime.h>
#include <stdint.h>

#define B_TOT 16384
#define F_NUM 24
#define P_NUM 276
#define BT    64          // b-rows per block (2 MFMA n-subtiles)
#define NTH   512
#define ROWP  776         // shorts per LDS row: 12 fields*64 + 8 pad (16B-aligned rows)

typedef float f32x16 __attribute__((ext_vector_type(16)));
typedef short bf16x8 __attribute__((ext_vector_type(8)));

__device__ inline unsigned short f2bf(float f) {
    unsigned u = __float_as_uint(f);
    u += 0x7fffu + ((u >> 16) & 1u);      // round-to-nearest-even
    return (unsigned short)(u >> 16);
}

// ---- pair schedule ---------------------------------------------------------
// Phase 1: pairs (i,j) with j<=11 (66), LDS holds fields 0..11 (jl = j).
// Phase 2: pairs (i,j) with j>=12 (210), LDS holds fields 12..23 (jl = j-12).
// Pairs sorted by i; waves take contiguous even-sized chunks; epilogue flag at
// every i-change or chunk end (partial epilogues are exact: out is linear in V).
// entry = p | (jl<<9) | (i<<13) | (flag<<18)
struct Tab { int ent[8][40]; int c1[8]; int c2[8]; };
constexpr Tab build_tab() {
    Tab t{};
    int list[210][3] = {};
    // ---- phase 1
    int n = 0;
    for (int i = 0; i < 12; ++i)
        for (int j = i + 1; j < 12; ++j) {
            list[n][0] = 23 * i - i * (i - 1) / 2 + (j - i - 1);
            list[n][1] = j;
            list[n][2] = i;
            ++n;                                   // 66
        }
    {
        const int cnts[8] = {10, 8, 8, 8, 8, 8, 8, 8};
        int pos = 0;
        for (int w = 0; w < 8; ++w) {
            t.c1[w] = cnts[w];
            for (int k = 0; k < cnts[w]; ++k, ++pos) {
                int flag = (k == cnts[w] - 1) ? 1
                         : ((list[pos + 1][2] != list[pos][2]) ? 1 : 0);
                t.ent[w][k] = list[pos][0] | (list[pos][1] << 9)
                            | (list[pos][2] << 13) | (flag << 18);
            }
        }
    }
    // ---- phase 2
    n = 0;
    for (int i = 0; i < 23; ++i) {
        int j0 = (i < 12) ? 12 : i + 1;
        for (int j = j0; j < 24; ++j) {
            list[n][0] = 23 * i - i * (i - 1) / 2 + (j - i - 1);
            list[n][1] = j - 12;
            list[n][2] = i;
            ++n;                                   // 210
        }
    }
    {
        const int cnts[8] = {26, 26, 26, 26, 26, 26, 26, 28};
        int pos = 0;
        for (int w = 0; w < 8; ++w) {
            t.c2[w] = cnts[w];
            for (int k = 0; k < cnts[w]; ++k, ++pos) {
                int flag = (k == cnts[w] - 1) ? 1
                         : ((list[pos + 1][2] != list[pos][2]) ? 1 : 0);
                t.ent[w][t.c1[w] + k] = list[pos][0] | (list[pos][1] << 9)
                                      | (list[pos][2] << 13) | (flag << 18);
            }
        }
    }
    return t;
}
__device__ __constant__ Tab gtab = build_tab();

// ---- prepass: W fp32 -> bf16 A-fragments, pair-major chunk layout ----------
// chunk(p, u) with u = ks*2+m at afrag[((p*8+u)*64 + lane)*8], 8 shorts/lane:
//   elem i = W[p][m*32 + (lane&31)][ks*16 + (lane>>5)*8 + i]
__global__ __launch_bounds__(256) void wprep(const float* __restrict__ W,
                                             unsigned short* __restrict__ afrag) {
    __shared__ __align__(16) unsigned short wlds[64 * 72];
    int p = blockIdx.x, t = threadIdx.x;
    const float4* src = (const float4*)(W + (size_t)p * 4096);
    #pragma unroll
    for (int c = 0; c < 4; ++c) {
        int i = t + c * 256;             // float4 index 0..1023 (coalesced)
        float4 v = src[i];
        int d = i >> 4;
        int e = (i & 15) * 4;
        ushort4 h; h.x=f2bf(v.x); h.y=f2bf(v.y); h.z=f2bf(v.z); h.w=f2bf(v.w);
        *(ushort4*)(&wlds[d * 72 + e]) = h;
    }
    __syncthreads();
    #pragma unroll
    for (int c = 0; c < 2; ++c) {
        int sl = t + c * 256;            // 0..511
        int u = sl >> 6, lane = sl & 63;
        int ks = u >> 1, m = u & 1;
        int d = m * 32 + (lane & 31);
        int e = ks * 16 + (lane >> 5) * 8;
        bf16x8 v = *(const bf16x8*)(&wlds[d * 72 + e]);
        *(bf16x8*)(afrag + ((size_t)(p * 8 + u) * 64 + lane) * 8) = v;
    }
}

// ---- main kernel -----------------------------------------------------------
__global__ __launch_bounds__(NTH, 2) void fmfm_main(const float* __restrict__ x,
                                                    const unsigned short* __restrict__ afrag,
                                                    float* __restrict__ out) {
    __shared__ __align__(16) unsigned short xs[BT * ROWP];   // 99,328 B
    __shared__ float t_red[BT];
    const int tid = threadIdx.x;
    const int btile = blockIdx.x;
    const int lane = tid & 63;
    const int wv = __builtin_amdgcn_readfirstlane(tid >> 6);
    const int bcol = lane & 31;
    const int q = lane >> 5;
    const int q8 = q * 8, q4 = q * 4;

    if (tid < BT) t_red[tid] = 0.0f;

    const bf16x8* afr = (const bf16x8*)afrag;
    const float* xg  = x + (size_t)btile * BT * 1536;
    const float* xe0 = xg + (size_t)bcol * 1536 + q4;        // epilogue, n=0 row
    const float* xe1 = xe0 + (size_t)32 * 1536;              // n=1 row
    const unsigned short* xr0 = xs + bcol * ROWP;
    const unsigned short* xr1 = xs + (bcol + 32) * ROWP;

    float tacc0 = 0.f, tacc1 = 0.f;
    f32x16 a00, a01, a10, a11;           // acc[n][m]
    #pragma unroll
    for (int i = 0; i < 16; ++i) { a00[i]=0.f; a01[i]=0.f; a10[i]=0.f; a11[i]=0.f; }

    bf16x8 bufA[8], bufB[8];
    auto lda = [&](int p, bf16x8* buf) {
        const bf16x8* ap = afr + (size_t)p * 512 + lane;
        #pragma unroll
        for (int u = 0; u < 8; ++u) buf[u] = ap[u * 64];
    };

    auto epi = [&](int i) {              // partial epilogue; x_i from global fp32
        const float* e0 = xe0 + i * 64;
        const float* e1 = xe1 + i * 64;
        #pragma unroll
        for (int g = 0; g < 4; ++g) {
            float4 v = *(const float4*)(e0 + 8 * g);
            tacc0 += a00[4*g+0]*v.x + a00[4*g+1]*v.y + a00[4*g+2]*v.z + a00[4*g+3]*v.w;
            v = *(const float4*)(e0 + 32 + 8 * g);
            tacc0 += a01[4*g+0]*v.x + a01[4*g+1]*v.y + a01[4*g+2]*v.z + a01[4*g+3]*v.w;
            v = *(const float4*)(e1 + 8 * g);
            tacc1 += a10[4*g+0]*v.x + a10[4*g+1]*v.y + a10[4*g+2]*v.z + a10[4*g+3]*v.w;
            v = *(const float4*)(e1 + 32 + 8 * g);
            tacc1 += a11[4*g+0]*v.x + a11[4*g+1]*v.y + a11[4*g+2]*v.z + a11[4*g+3]*v.w;
        }
        #pragma unroll
        for (int k = 0; k < 16; ++k) { a00[k]=0.f; a01[k]=0.f; a10[k]=0.f; a11[k]=0.f; }
    };

    // one step = one pair: 8 LDS b-frags, 16 MFMAs (4 chains), depth-2 W prefetch
    auto step = [&](int idx, int nxt, bf16x8* buf) {
        int e = gtab.ent[wv][idx];
        int jb = ((e >> 9) & 15) * 64 + q8;
        int fi = (e >> 13) & 31;
        const unsigned short* b0p = xr0 + jb;
        const unsigned short* b1p = xr1 + jb;
        bf16x8 b0k0 = *(const bf16x8*)(b0p);
        bf16x8 b0k1 = *(const bf16x8*)(b0p + 16);
        bf16x8 b0k2 = *(const bf16x8*)(b0p + 32);
        bf16x8 b0k3 = *(const bf16x8*)(b0p + 48);
        bf16x8 b1k0 = *(const bf16x8*)(b1p);
        bf16x8 b1k1 = *(const bf16x8*)(b1p + 16);
        bf16x8 b1k2 = *(const bf16x8*)(b1p + 32);
        bf16x8 b1k3 = *(const bf16x8*)(b1p + 48);
        a00 = __builtin_amdgcn_mfma_f32_32x32x16_bf16(buf[0], b0k0, a00, 0, 0, 0);
        a01 = __builtin_amdgcn_mfma_f32_32x32x16_bf16(buf[1], b0k0, a01, 0, 0, 0);
        a10 = __builtin_amdgcn_mfma_f32_32x32x16_bf16(buf[0], b1k0, a10, 0, 0, 0);
        a11 = __builtin_amdgcn_mfma_f32_32x32x16_bf16(buf[1], b1k0, a11, 0, 0, 0);
        a00 = __builtin_amdgcn_mfma_f32_32x32x16_bf16(buf[2], b0k1, a00, 0, 0, 0);
        a01 = __builtin_amdgcn_mfma_f32_32x32x16_bf16(buf[3], b0k1, a01, 0, 0, 0);
        a10 = __builtin_amdgcn_mfma_f32_32x32x16_bf16(buf[2], b1k1, a10, 0, 0, 0);
        a11 = __builtin_amdgcn_mfma_f32_32x32x16_bf16(buf[3], b1k1, a11, 0, 0, 0);
        a00 = __builtin_amdgcn_mfma_f32_32x32x16_bf16(buf[4], b0k2, a00, 0, 0, 0);
        a01 = __builtin_amdgcn_mfma_f32_32x32x16_bf16(buf[5], b0k2, a01, 0, 0, 0);
        a10 = __builtin_amdgcn_mfma_f32_32x32x16_bf16(buf[4], b1k2, a10, 0, 0, 0);
        a11 = __builtin_amdgcn_mfma_f32_32x32x16_bf16(buf[5], b1k2, a11, 0, 0, 0);
        a00 = __builtin_amdgcn_mfma_f32_32x32x16_bf16(buf[6], b0k3, a00, 0, 0, 0);
        a01 = __builtin_amdgcn_mfma_f32_32x32x16_bf16(buf[7], b0k3, a01, 0, 0, 0);
        a10 = __builtin_amdgcn_mfma_f32_32x32x16_bf16(buf[6], b1k3, a10, 0, 0, 0);
        a11 = __builtin_amdgcn_mfma_f32_32x32x16_bf16(buf[7], b1k3, a11, 0, 0, 0);
        lda(gtab.ent[wv][nxt] & 511, buf);
        if (e & (1 << 18)) epi(fi);      // wave-uniform
    };

    #pragma unroll 1
    for (int ph = 0; ph < 2; ++ph) {
        int base = ph ? gtab.c1[wv] : 0;
        int cnt  = ph ? gtab.c2[wv] : gtab.c1[wv];
        // prefetch first two pairs' W BEFORE staging: loads fly during the stage
        lda(gtab.ent[wv][base] & 511, bufA);
        lda(gtab.ent[wv][base + 1] & 511, bufB);
        __syncthreads();                 // protect LDS from previous phase readers
        // stage field-half ph: 64 rows x 3KB, fully contiguous reads
        const float* src = xg + ph * 768;
        #pragma unroll
        for (int c = 0; c < 24; ++c) {
            int idx = tid + c * NTH;     // 0..12287
            int row = idx / 192;
            int c4  = idx - row * 192;
            float4 v = *(const float4*)(src + (size_t)row * 1536 + c4 * 4);
            ushort4 h; h.x=f2bf(v.x); h.y=f2bf(v.y); h.z=f2bf(v.z); h.w=f2bf(v.w);
            *(ushort4*)(&xs[row * ROWP + c4 * 4]) = h;
        }
        __syncthreads();
        int end = base + cnt;
        for (int s = base; s < end; s += 2) {    // even cnt; ping-pong
            int n0 = (s + 2 < end) ? s + 2 : end - 1;
            int n1 = (s + 3 < end) ? s + 3 : end - 1;
            step(s,     n0, bufA);
            step(s + 1, n1, bufB);
        }
    }

    atomicAdd(&t_red[bcol],      tacc0);
    atomicAdd(&t_red[bcol + 32], tacc1);
    __syncthreads();
    if (tid < BT) out[(size_t)btile * BT + tid] = t_red[tid];
}

extern "C" void kernel_launch(void* const* d_in, const int* in_sizes, int n_in,
                              void* d_out, int out_size, void* d_ws, size_t ws_size,
                              hipStream_t stream) {
    const float* x = (const float*)d_in[0];
    const float* W = (const float*)d_in[1];
    float* out = (float*)d_out;
    unsigned short* afrag = (unsigned short*)d_ws;   // 2.26 MB scratch
    wprep<<<P_NUM, 256, 0, stream>>>(W, afrag);
    fmfm_main<<<B_TOT / BT, NTH, 0, stream>>>(x, afrag, out);
}

// Round 5
// 212.575 us; speedup vs baseline: 1.0700x; 1.0625x over previous
//
#include <hip/hip_runtime.h>
#include <stdint.h>

#define B_TOT 16384
#define F_NUM 24
#define P_NUM 276
#define BT    64          // b-rows per block (2 MFMA n-subtiles)
#define NTH   512
#define ROWP  776         // shorts per LDS row: 12 fields*64 + 8 pad

typedef float f32x16 __attribute__((ext_vector_type(16)));
typedef short bf16x8 __attribute__((ext_vector_type(8)));

__device__ inline unsigned short f2bf(float f) {
    unsigned u = __float_as_uint(f);
    u += 0x7fffu + ((u >> 16) & 1u);      // round-to-nearest-even
    return (unsigned short)(u >> 16);
}
__device__ inline float bf2f(unsigned short h) {
    return __uint_as_float(((unsigned)h) << 16);
}

// ---- pair schedule ---------------------------------------------------------
// Phase 1: pairs (i,j) j<=11 (66), LDS = fields 0..11.  epi from LDS (eidx=i).
// Phase 2: pairs (i,j) j>=12 (210), LDS = fields 12..23. epi from LDS (eidx=i-12)
//          when i>=12, else from global fp32 (eglob=1, eidx=i).
// Pairs sorted by i; contiguous even chunks per wave; epilogue flag at i-change
// or chunk end (partial epilogues exact: out is linear in V).
// entry = p | (jl<<9) | (eidx<<13) | (eflag<<18) | (eglob<<19)
struct Tab { int ent[8][40]; int c1[8]; int c2[8]; };
constexpr Tab build_tab() {
    Tab t{};
    int list[210][3] = {};
    int n = 0;
    for (int i = 0; i < 12; ++i)
        for (int j = i + 1; j < 12; ++j) {
            list[n][0] = 23 * i - i * (i - 1) / 2 + (j - i - 1);
            list[n][1] = j; list[n][2] = i; ++n;        // 66
        }
    {
        const int cnts[8] = {10, 8, 8, 8, 8, 8, 8, 8};
        int pos = 0;
        for (int w = 0; w < 8; ++w) {
            t.c1[w] = cnts[w];
            for (int k = 0; k < cnts[w]; ++k, ++pos) {
                int flag = (k == cnts[w] - 1) || (list[pos + 1][2] != list[pos][2]);
                t.ent[w][k] = list[pos][0] | (list[pos][1] << 9)
                            | (list[pos][2] << 13) | (flag << 18);
            }
        }
    }
    n = 0;
    for (int i = 0; i < 23; ++i) {
        int j0 = (i < 12) ? 12 : i + 1;
        for (int j = j0; j < 24; ++j) {
            list[n][0] = 23 * i - i * (i - 1) / 2 + (j - i - 1);
            list[n][1] = j - 12; list[n][2] = i; ++n;   // 210
        }
    }
    {
        const int cnts[8] = {26, 26, 26, 26, 26, 26, 26, 28};
        int pos = 0;
        for (int w = 0; w < 8; ++w) {
            t.c2[w] = cnts[w];
            for (int k = 0; k < cnts[w]; ++k, ++pos) {
                int flag = (k == cnts[w] - 1) || (list[pos + 1][2] != list[pos][2]);
                int i = list[pos][2];
                int eglob = (i < 12) ? 1 : 0;
                int eidx  = (i < 12) ? i : (i - 12);
                t.ent[w][t.c1[w] + k] = list[pos][0] | (list[pos][1] << 9)
                                      | (eidx << 13) | (flag << 18) | (eglob << 19);
            }
        }
    }
    return t;
}
__device__ __constant__ Tab gtab = build_tab();

// ---- prepass: W fp32 -> bf16 A-fragments, pair-major chunk layout ----------
// chunk(p, u) u=ks*2+m at afrag[((p*8+u)*64 + lane)*8]:
//   elem i = W[p][m*32 + (lane&31)][ks*16 + (lane>>5)*8 + i]
__global__ __launch_bounds__(256) void wprep(const float* __restrict__ W,
                                             unsigned short* __restrict__ afrag) {
    __shared__ __align__(16) unsigned short wlds[64 * 72];
    int p = blockIdx.x, t = threadIdx.x;
    const float4* src = (const float4*)(W + (size_t)p * 4096);
    #pragma unroll
    for (int c = 0; c < 4; ++c) {
        int i = t + c * 256;
        float4 v = src[i];
        int d = i >> 4;
        int e = (i & 15) * 4;
        ushort4 h; h.x=f2bf(v.x); h.y=f2bf(v.y); h.z=f2bf(v.z); h.w=f2bf(v.w);
        *(ushort4*)(&wlds[d * 72 + e]) = h;
    }
    __syncthreads();
    #pragma unroll
    for (int c = 0; c < 2; ++c) {
        int sl = t + c * 256;
        int u = sl >> 6, lane = sl & 63;
        int ks = u >> 1, m = u & 1;
        int d = m * 32 + (lane & 31);
        int e = ks * 16 + (lane >> 5) * 8;
        bf16x8 v = *(const bf16x8*)(&wlds[d * 72 + e]);
        *(bf16x8*)(afrag + ((size_t)(p * 8 + u) * 64 + lane) * 8) = v;
    }
}

// ---- macros: named-variable W buffers (NO arrays -> guaranteed SROA) -------
#define LDA8(P, A0,A1,A2,A3,A4,A5,A6,A7) do {                                  \
    const bf16x8* ap_ = afr + (size_t)(P) * 512 + lane;                        \
    A0 = ap_[0];   A1 = ap_[64];  A2 = ap_[128]; A3 = ap_[192];                \
    A4 = ap_[256]; A5 = ap_[320]; A6 = ap_[384]; A7 = ap_[448]; } while (0)

#define STEP(S_, N_, A0,A1,A2,A3,A4,A5,A6,A7) do {                             \
    int e_  = gtab.ent[wv][S_];                                                \
    int jb_ = ((e_ >> 9) & 15) * 64 + q8;                                      \
    const unsigned short* b0p_ = xr0 + jb_;                                    \
    const unsigned short* b1p_ = xr1 + jb_;                                    \
    bf16x8 b00_ = *(const bf16x8*)(b0p_);                                      \
    bf16x8 b01_ = *(const bf16x8*)(b0p_ + 16);                                 \
    bf16x8 b02_ = *(const bf16x8*)(b0p_ + 32);                                 \
    bf16x8 b03_ = *(const bf16x8*)(b0p_ + 48);                                 \
    bf16x8 b10_ = *(const bf16x8*)(b1p_);                                      \
    bf16x8 b11_ = *(const bf16x8*)(b1p_ + 16);                                 \
    bf16x8 b12_ = *(const bf16x8*)(b1p_ + 32);                                 \
    bf16x8 b13_ = *(const bf16x8*)(b1p_ + 48);                                 \
    a00 = __builtin_amdgcn_mfma_f32_32x32x16_bf16(A0, b00_, a00, 0, 0, 0);     \
    a01 = __builtin_amdgcn_mfma_f32_32x32x16_bf16(A1, b00_, a01, 0, 0, 0);     \
    a10 = __builtin_amdgcn_mfma_f32_32x32x16_bf16(A0, b10_, a10, 0, 0, 0);     \
    a11 = __builtin_amdgcn_mfma_f32_32x32x16_bf16(A1, b10_, a11, 0, 0, 0);     \
    a00 = __builtin_amdgcn_mfma_f32_32x32x16_bf16(A2, b01_, a00, 0, 0, 0);     \
    a01 = __builtin_amdgcn_mfma_f32_32x32x16_bf16(A3, b01_, a01, 0, 0, 0);     \
    a10 = __builtin_amdgcn_mfma_f32_32x32x16_bf16(A2, b11_, a10, 0, 0, 0);     \
    a11 = __builtin_amdgcn_mfma_f32_32x32x16_bf16(A3, b11_, a11, 0, 0, 0);     \
    a00 = __builtin_amdgcn_mfma_f32_32x32x16_bf16(A4, b02_, a00, 0, 0, 0);     \
    a01 = __builtin_amdgcn_mfma_f32_32x32x16_bf16(A5, b02_, a01, 0, 0, 0);     \
    a10 = __builtin_amdgcn_mfma_f32_32x32x16_bf16(A4, b12_, a10, 0, 0, 0);     \
    a11 = __builtin_amdgcn_mfma_f32_32x32x16_bf16(A5, b12_, a11, 0, 0, 0);     \
    a00 = __builtin_amdgcn_mfma_f32_32x32x16_bf16(A6, b03_, a00, 0, 0, 0);     \
    a01 = __builtin_amdgcn_mfma_f32_32x32x16_bf16(A7, b03_, a01, 0, 0, 0);     \
    a10 = __builtin_amdgcn_mfma_f32_32x32x16_bf16(A6, b13_, a10, 0, 0, 0);     \
    a11 = __builtin_amdgcn_mfma_f32_32x32x16_bf16(A7, b13_, a11, 0, 0, 0);     \
    int pn_ = gtab.ent[wv][N_] & 511;                                          \
    LDA8(pn_, A0,A1,A2,A3,A4,A5,A6,A7);                                        \
    if (e_ & (1 << 18)) {                                                      \
        int fx_ = (e_ >> 13) & 31;                                             \
        if (e_ & (1 << 19)) epi_glb(fx_); else epi_lds(fx_);                   \
        zacc();                                                                \
    } } while (0)

// ---- main kernel -----------------------------------------------------------
__global__ __launch_bounds__(NTH, 2) void fmfm_main(const float* __restrict__ x,
                                                    const unsigned short* __restrict__ afrag,
                                                    float* __restrict__ out) {
    __shared__ __align__(16) unsigned short xs[BT * ROWP];   // 99,328 B
    __shared__ float t_red[BT];
    const int tid = threadIdx.x;
    const int btile = blockIdx.x;
    const int lane = tid & 63;
    const int wv = __builtin_amdgcn_readfirstlane(tid >> 6);
    const int bcol = lane & 31;
    const int q = lane >> 5;
    const int q8 = q * 8, q4 = q * 4;

    if (tid < BT) t_red[tid] = 0.0f;

    const bf16x8* afr = (const bf16x8*)afrag;
    const float* xg  = x + (size_t)btile * BT * 1536;
    const float* xe0 = xg + (size_t)bcol * 1536 + q4;        // global epi, n=0 row
    const float* xe1 = xe0 + (size_t)32 * 1536;              // n=1 row
    const unsigned short* xr0 = xs + bcol * ROWP;
    const unsigned short* xr1 = xs + (bcol + 32) * ROWP;

    float tacc0 = 0.f, tacc1 = 0.f;
    f32x16 a00, a01, a10, a11;           // acc[n][m]
    auto zacc = [&]() {
        #pragma unroll
        for (int k = 0; k < 16; ++k) { a00[k]=0.f; a01[k]=0.f; a10[k]=0.f; a11[k]=0.f; }
    };
    zacc();

    // epilogue from LDS bf16 (i-field resident in current phase)
    auto epi_lds = [&](int fl) {
        const unsigned short* e0 = xr0 + fl * 64 + q4;
        const unsigned short* e1 = xr1 + fl * 64 + q4;
        #pragma unroll
        for (int g = 0; g < 4; ++g) {
            ushort4 u0 = *(const ushort4*)(e0 + 8 * g);
            tacc0 += a00[4*g+0]*bf2f(u0.x) + a00[4*g+1]*bf2f(u0.y)
                   + a00[4*g+2]*bf2f(u0.z) + a00[4*g+3]*bf2f(u0.w);
            u0 = *(const ushort4*)(e0 + 32 + 8 * g);
            tacc0 += a01[4*g+0]*bf2f(u0.x) + a01[4*g+1]*bf2f(u0.y)
                   + a01[4*g+2]*bf2f(u0.z) + a01[4*g+3]*bf2f(u0.w);
            u0 = *(const ushort4*)(e1 + 8 * g);
            tacc1 += a10[4*g+0]*bf2f(u0.x) + a10[4*g+1]*bf2f(u0.y)
                   + a10[4*g+2]*bf2f(u0.z) + a10[4*g+3]*bf2f(u0.w);
            u0 = *(const ushort4*)(e1 + 32 + 8 * g);
            tacc1 += a11[4*g+0]*bf2f(u0.x) + a11[4*g+1]*bf2f(u0.y)
                   + a11[4*g+2]*bf2f(u0.z) + a11[4*g+3]*bf2f(u0.w);
        }
    };
    // epilogue from global fp32 (phase-2 cross pairs, i<12)
    auto epi_glb = [&](int fi) {
        const float* e0 = xe0 + fi * 64;
        const float* e1 = xe1 + fi * 64;
        #pragma unroll
        for (int g = 0; g < 4; ++g) {
            float4 v = *(const float4*)(e0 + 8 * g);
            tacc0 += a00[4*g+0]*v.x + a00[4*g+1]*v.y + a00[4*g+2]*v.z + a00[4*g+3]*v.w;
            v = *(const float4*)(e0 + 32 + 8 * g);
            tacc0 += a01[4*g+0]*v.x + a01[4*g+1]*v.y + a01[4*g+2]*v.z + a01[4*g+3]*v.w;
            v = *(const float4*)(e1 + 8 * g);
            tacc1 += a10[4*g+0]*v.x + a10[4*g+1]*v.y + a10[4*g+2]*v.z + a10[4*g+3]*v.w;
            v = *(const float4*)(e1 + 32 + 8 * g);
            tacc1 += a11[4*g+0]*v.x + a11[4*g+1]*v.y + a11[4*g+2]*v.z + a11[4*g+3]*v.w;
        }
    };

    bf16x8 A0,A1,A2,A3,A4,A5,A6,A7;      // W ping buffer (named: register-resident)
    bf16x8 B0,B1,B2,B3,B4,B5,B6,B7;      // W pong buffer

    #pragma unroll 1
    for (int ph = 0; ph < 2; ++ph) {
        int base = ph ? gtab.c1[wv] : 0;
        int cnt  = ph ? gtab.c2[wv] : gtab.c1[wv];
        int end  = base + cnt;
        // prefetch first two pairs' W BEFORE staging: loads fly during the stage
        LDA8(gtab.ent[wv][base] & 511,     A0,A1,A2,A3,A4,A5,A6,A7);
        LDA8(gtab.ent[wv][base + 1] & 511, B0,B1,B2,B3,B4,B5,B6,B7);
        __syncthreads();                 // protect LDS from previous phase readers
        // stage field-half ph: 64 rows x 3KB, fully contiguous reads
        const float* src = xg + ph * 768;
        #pragma unroll
        for (int c = 0; c < 24; ++c) {
            int idx = tid + c * NTH;     // 0..12287
            int row = idx / 192;
            int c4  = idx - row * 192;
            float4 v = *(const float4*)(src + (size_t)row * 1536 + c4 * 4);
            ushort4 h; h.x=f2bf(v.x); h.y=f2bf(v.y); h.z=f2bf(v.z); h.w=f2bf(v.w);
            *(ushort4*)(&xs[row * ROWP + c4 * 4]) = h;
        }
        __syncthreads();
        #pragma unroll 1
        for (int s = base; s < end; s += 2) {    // even cnt; ping-pong
            int n0 = (s + 2 < end) ? s + 2 : end - 1;
            int n1 = (s + 3 < end) ? s + 3 : end - 1;
            STEP(s,     n0, A0,A1,A2,A3,A4,A5,A6,A7);
            STEP(s + 1, n1, B0,B1,B2,B3,B4,B5,B6,B7);
        }
    }

    atomicAdd(&t_red[bcol],      tacc0);
    atomicAdd(&t_red[bcol + 32], tacc1);
    __syncthreads();
    if (tid < BT) out[(size_t)btile * BT + tid] = t_red[tid];
}

extern "C" void kernel_launch(void* const* d_in, const int* in_sizes, int n_in,
                              void* d_out, int out_size, void* d_ws, size_t ws_size,
                              hipStream_t stream) {
    const float* x = (const float*)d_in[0];
    const float* W = (const float*)d_in[1];
    float* out = (float*)d_out;
    unsigned short* afrag = (unsigned short*)d_ws;   // 2.26 MB scratch
    wprep<<<P_NUM, 256, 0, stream>>>(W, afrag);
    fmfm_main<<<B_TOT / BT, NTH, 0, stream>>>(x, afrag, out);
}

// Round 6
// 193.053 us; speedup vs baseline: 1.1782x; 1.1011x over previous
//
#include <hip/hip_runtime.h>
#include <stdint.h>

#define B_TOT 16384
#define F_NUM 24
#define P_NUM 276
#define BT    64          // b-rows per block (2 MFMA n-subtiles)
#define NTH   512
#define ROWP  776         // shorts per LDS row: 12 fields*64 + 8 pad

typedef float f32x16 __attribute__((ext_vector_type(16)));
typedef short bf16x8 __attribute__((ext_vector_type(8)));

__device__ inline unsigned short f2bf(float f) {
    unsigned u = __float_as_uint(f);
    u += 0x7fffu + ((u >> 16) & 1u);      // round-to-nearest-even
    return (unsigned short)(u >> 16);
}
__device__ inline float bf2f(unsigned short h) {
    return __uint_as_float(((unsigned)h) << 16);
}

// ---- pair schedule ---------------------------------------------------------
// Phase 1: pairs (i,j) j<=11 (66), LDS = fields 0..11.  epi from LDS (eidx=i).
// Phase 2: pairs (i,j) j>=12 (210), LDS = fields 12..23. epi from LDS (eidx=i-12)
//          when i>=12, else from global fp32 (eglob=1, eidx=i).
// Pairs sorted by i; contiguous chunks per wave; epilogue flag at i-change or
// chunk end (partial epilogues exact: out is linear in V).
// entry = p | (jl<<9) | (eidx<<13) | (eflag<<18) | (eglob<<19)
struct Tab { int ent[8][40]; int c1[8]; int c2[8]; };
constexpr Tab build_tab() {
    Tab t{};
    int list[210][3] = {};
    int n = 0;
    for (int i = 0; i < 12; ++i)
        for (int j = i + 1; j < 12; ++j) {
            list[n][0] = 23 * i - i * (i - 1) / 2 + (j - i - 1);
            list[n][1] = j; list[n][2] = i; ++n;        // 66
        }
    {
        const int cnts[8] = {10, 8, 8, 8, 8, 8, 8, 8};
        int pos = 0;
        for (int w = 0; w < 8; ++w) {
            t.c1[w] = cnts[w];
            for (int k = 0; k < cnts[w]; ++k, ++pos) {
                int flag = (k == cnts[w] - 1) || (list[pos + 1][2] != list[pos][2]);
                t.ent[w][k] = list[pos][0] | (list[pos][1] << 9)
                            | (list[pos][2] << 13) | (flag << 18);
            }
        }
    }
    n = 0;
    for (int i = 0; i < 23; ++i) {
        int j0 = (i < 12) ? 12 : i + 1;
        for (int j = j0; j < 24; ++j) {
            list[n][0] = 23 * i - i * (i - 1) / 2 + (j - i - 1);
            list[n][1] = j - 12; list[n][2] = i; ++n;   // 210
        }
    }
    {
        const int cnts[8] = {26, 26, 26, 26, 26, 26, 26, 28};
        int pos = 0;
        for (int w = 0; w < 8; ++w) {
            t.c2[w] = cnts[w];
            for (int k = 0; k < cnts[w]; ++k, ++pos) {
                int flag = (k == cnts[w] - 1) || (list[pos + 1][2] != list[pos][2]);
                int i = list[pos][2];
                int eglob = (i < 12) ? 1 : 0;
                int eidx  = (i < 12) ? i : (i - 12);
                t.ent[w][t.c1[w] + k] = list[pos][0] | (list[pos][1] << 9)
                                      | (eidx << 13) | (flag << 18) | (eglob << 19);
            }
        }
    }
    return t;
}
__device__ __constant__ Tab gtab = build_tab();

// ---- prepass: W fp32 -> bf16 A-fragments, pair-major chunk layout ----------
// chunk(p, u) u=ks*2+m at afrag[((p*8+u)*64 + lane)*8]:
//   elem i = W[p][m*32 + (lane&31)][ks*16 + (lane>>5)*8 + i]
__global__ __launch_bounds__(256) void wprep(const float* __restrict__ W,
                                             unsigned short* __restrict__ afrag) {
    __shared__ __align__(16) unsigned short wlds[64 * 72];
    int p = blockIdx.x, t = threadIdx.x;
    const float4* src = (const float4*)(W + (size_t)p * 4096);
    #pragma unroll
    for (int c = 0; c < 4; ++c) {
        int i = t + c * 256;
        float4 v = src[i];
        int d = i >> 4;
        int e = (i & 15) * 4;
        ushort4 h; h.x=f2bf(v.x); h.y=f2bf(v.y); h.z=f2bf(v.z); h.w=f2bf(v.w);
        *(ushort4*)(&wlds[d * 72 + e]) = h;
    }
    __syncthreads();
    #pragma unroll
    for (int c = 0; c < 2; ++c) {
        int sl = t + c * 256;
        int u = sl >> 6, lane = sl & 63;
        int ks = u >> 1, m = u & 1;
        int d = m * 32 + (lane & 31);
        int e = ks * 16 + (lane >> 5) * 8;
        bf16x8 v = *(const bf16x8*)(&wlds[d * 72 + e]);
        *(bf16x8*)(afrag + ((size_t)(p * 8 + u) * 64 + lane) * 8) = v;
    }
}

// ---- macros: 4-chunk W buffers, named vars only (register-resident) --------
// HALF in {0,1}: chunk group u = HALF*4 .. HALF*4+3
#define LDA4(P_, HALF_, A0,A1,A2,A3) do {                                      \
    const bf16x8* ap_ = afr + (size_t)(P_) * 512 + (HALF_) * 256 + lane;       \
    A0 = ap_[0]; A1 = ap_[64]; A2 = ap_[128]; A3 = ap_[192]; } while (0)

// half-step: 2 k-steps (4 B-frag LDS reads), 8 MFMAs, refill own buffer
#define HSTEP(E_, NP_, HALF_, A0,A1,A2,A3) do {                                \
    int jb_ = ((E_ >> 9) & 15) * 64 + q8 + (HALF_) * 32;                       \
    const unsigned short* b0p_ = xr0 + jb_;                                    \
    const unsigned short* b1p_ = xr1 + jb_;                                    \
    bf16x8 b00_ = *(const bf16x8*)(b0p_);                                      \
    bf16x8 b01_ = *(const bf16x8*)(b0p_ + 16);                                 \
    bf16x8 b10_ = *(const bf16x8*)(b1p_);                                      \
    bf16x8 b11_ = *(const bf16x8*)(b1p_ + 16);                                 \
    a00 = __builtin_amdgcn_mfma_f32_32x32x16_bf16(A0, b00_, a00, 0, 0, 0);     \
    a01 = __builtin_amdgcn_mfma_f32_32x32x16_bf16(A1, b00_, a01, 0, 0, 0);     \
    a10 = __builtin_amdgcn_mfma_f32_32x32x16_bf16(A0, b10_, a10, 0, 0, 0);     \
    a11 = __builtin_amdgcn_mfma_f32_32x32x16_bf16(A1, b10_, a11, 0, 0, 0);     \
    a00 = __builtin_amdgcn_mfma_f32_32x32x16_bf16(A2, b01_, a00, 0, 0, 0);     \
    a01 = __builtin_amdgcn_mfma_f32_32x32x16_bf16(A3, b01_, a01, 0, 0, 0);     \
    a10 = __builtin_amdgcn_mfma_f32_32x32x16_bf16(A2, b11_, a10, 0, 0, 0);     \
    a11 = __builtin_amdgcn_mfma_f32_32x32x16_bf16(A3, b11_, a11, 0, 0, 0);     \
    LDA4(NP_, HALF_, A0,A1,A2,A3); } while (0)

// ---- main kernel -----------------------------------------------------------
__global__ __launch_bounds__(NTH, 2) void fmfm_main(const float* __restrict__ x,
                                                    const unsigned short* __restrict__ afrag,
                                                    float* __restrict__ out) {
    __shared__ __align__(16) unsigned short xs[BT * ROWP];   // 99,328 B
    __shared__ float t_red[BT];
    const int tid = threadIdx.x;
    const int btile = blockIdx.x;
    const int lane = tid & 63;
    const int wv = __builtin_amdgcn_readfirstlane(tid >> 6);
    const int bcol = lane & 31;
    const int q = lane >> 5;
    const int q8 = q * 8, q4 = q * 4;

    if (tid < BT) t_red[tid] = 0.0f;

    const bf16x8* afr = (const bf16x8*)afrag;
    const float* xg  = x + (size_t)btile * BT * 1536;
    const float* xe0 = xg + (size_t)bcol * 1536 + q4;        // global epi, n=0 row
    const float* xe1 = xe0 + (size_t)32 * 1536;              // n=1 row
    const unsigned short* xr0 = xs + bcol * ROWP;
    const unsigned short* xr1 = xs + (bcol + 32) * ROWP;

    float tacc0 = 0.f, tacc1 = 0.f;
    f32x16 a00, a01, a10, a11;           // acc[n][m]
    auto zacc = [&]() {
        #pragma unroll
        for (int k = 0; k < 16; ++k) { a00[k]=0.f; a01[k]=0.f; a10[k]=0.f; a11[k]=0.f; }
    };
    zacc();

    // epilogue from LDS bf16 (i-field resident in current phase)
    auto epi_lds = [&](int fl) {
        const unsigned short* e0 = xr0 + fl * 64 + q4;
        const unsigned short* e1 = xr1 + fl * 64 + q4;
        #pragma unroll
        for (int g = 0; g < 4; ++g) {
            ushort4 u0 = *(const ushort4*)(e0 + 8 * g);
            tacc0 += a00[4*g+0]*bf2f(u0.x) + a00[4*g+1]*bf2f(u0.y)
                   + a00[4*g+2]*bf2f(u0.z) + a00[4*g+3]*bf2f(u0.w);
            u0 = *(const ushort4*)(e0 + 32 + 8 * g);
            tacc0 += a01[4*g+0]*bf2f(u0.x) + a01[4*g+1]*bf2f(u0.y)
                   + a01[4*g+2]*bf2f(u0.z) + a01[4*g+3]*bf2f(u0.w);
            u0 = *(const ushort4*)(e1 + 8 * g);
            tacc1 += a10[4*g+0]*bf2f(u0.x) + a10[4*g+1]*bf2f(u0.y)
                   + a10[4*g+2]*bf2f(u0.z) + a10[4*g+3]*bf2f(u0.w);
            u0 = *(const ushort4*)(e1 + 32 + 8 * g);
            tacc1 += a11[4*g+0]*bf2f(u0.x) + a11[4*g+1]*bf2f(u0.y)
                   + a11[4*g+2]*bf2f(u0.z) + a11[4*g+3]*bf2f(u0.w);
        }
    };
    // epilogue from global fp32 (phase-2 cross pairs, i<12)
    auto epi_glb = [&](int fi) {
        const float* e0 = xe0 + fi * 64;
        const float* e1 = xe1 + fi * 64;
        #pragma unroll
        for (int g = 0; g < 4; ++g) {
            float4 v = *(const float4*)(e0 + 8 * g);
            tacc0 += a00[4*g+0]*v.x + a00[4*g+1]*v.y + a00[4*g+2]*v.z + a00[4*g+3]*v.w;
            v = *(const float4*)(e0 + 32 + 8 * g);
            tacc0 += a01[4*g+0]*v.x + a01[4*g+1]*v.y + a01[4*g+2]*v.z + a01[4*g+3]*v.w;
            v = *(const float4*)(e1 + 8 * g);
            tacc1 += a10[4*g+0]*v.x + a10[4*g+1]*v.y + a10[4*g+2]*v.z + a10[4*g+3]*v.w;
            v = *(const float4*)(e1 + 32 + 8 * g);
            tacc1 += a11[4*g+0]*v.x + a11[4*g+1]*v.y + a11[4*g+2]*v.z + a11[4*g+3]*v.w;
        }
    };

    bf16x8 A0,A1,A2,A3;                  // W buffer, ks{0,1} of current pair
    bf16x8 B0,B1,B2,B3;                  // W buffer, ks{2,3} of current pair

    #pragma unroll 1
    for (int ph = 0; ph < 2; ++ph) {
        int base = ph ? gtab.c1[wv] : 0;
        int cnt  = ph ? gtab.c2[wv] : gtab.c1[wv];
        int end  = base + cnt;
        // prefetch first pair's W BEFORE staging: loads fly during the stage
        int p0 = gtab.ent[wv][base] & 511;
        LDA4(p0, 0, A0,A1,A2,A3);
        LDA4(p0, 1, B0,B1,B2,B3);
        __syncthreads();                 // protect LDS from previous phase readers
        // stage field-half ph: 64 rows x 3KB, fully contiguous reads
        const float* src = xg + ph * 768;
        #pragma unroll 8
        for (int c = 0; c < 24; ++c) {
            int idx = tid + c * NTH;     // 0..12287
            int row = idx / 192;
            int c4  = idx - row * 192;
            float4 v = *(const float4*)(src + (size_t)row * 1536 + c4 * 4);
            ushort4 h; h.x=f2bf(v.x); h.y=f2bf(v.y); h.z=f2bf(v.z); h.w=f2bf(v.w);
            *(ushort4*)(&xs[row * ROWP + c4 * 4]) = h;
        }
        __syncthreads();
        #pragma unroll 1
        for (int s = base; s < end; ++s) {
            int e  = gtab.ent[wv][s];
            int sn = (s + 1 < end) ? s + 1 : s;
            int np = gtab.ent[wv][sn] & 511;
            HSTEP(e, np, 0, A0,A1,A2,A3);            // ks 0,1 + refill A(next)
            HSTEP(e, np, 1, B0,B1,B2,B3);            // ks 2,3 + refill B(next)
            if (e & (1 << 18)) {                     // wave-uniform epilogue
                int fx = (e >> 13) & 31;
                if (e & (1 << 19)) epi_glb(fx); else epi_lds(fx);
                zacc();
            }
        }
    }

    atomicAdd(&t_red[bcol],      tacc0);
    atomicAdd(&t_red[bcol + 32], tacc1);
    __syncthreads();
    if (tid < BT) out[(size_t)btile * BT + tid] = t_red[tid];
}

extern "C" void kernel_launch(void* const* d_in, const int* in_sizes, int n_in,
                              void* d_out, int out_size, void* d_ws, size_t ws_size,
                              hipStream_t stream) {
    const float* x = (const float*)d_in[0];
    const float* W = (const float*)d_in[1];
    float* out = (float*)d_out;
    unsigned short* afrag = (unsigned short*)d_ws;   // 2.26 MB scratch
    wprep<<<P_NUM, 256, 0, stream>>>(W, afrag);
    fmfm_main<<<B_TOT / BT, NTH, 0, stream>>>(x, afrag, out);
}

// Round 7
// 191.955 us; speedup vs baseline: 1.1850x; 1.0057x over previous
//
#include <hip/hip_runtime.h>
#include <stdint.h>

#define B_TOT 16384
#define F_NUM 24
#define P_NUM 276
#define BT    64          // b-rows per block (2 MFMA n-subtiles)
#define NTH   512
#define ROWP  776         // shorts per LDS row: 12 fields*64 + 8 pad

typedef float f32x16 __attribute__((ext_vector_type(16)));
typedef short bf16x8 __attribute__((ext_vector_type(8)));

__device__ inline unsigned short f2bf(float f) {
    unsigned u = __float_as_uint(f);
    u += 0x7fffu + ((u >> 16) & 1u);      // round-to-nearest-even
    return (unsigned short)(u >> 16);
}
__device__ inline float bf2f(unsigned short h) {
    return __uint_as_float(((unsigned)h) << 16);
}

// ---- pair schedule ---------------------------------------------------------
// Phase 1: pairs (i,j) j<=11 (66), LDS = fields 0..11.  epi from LDS (eidx=i).
// Phase 2: pairs (i,j) j>=12 (210), LDS = fields 12..23. epi from LDS (eidx=i-12)
//          when i>=12, else from global fp32 (eglob=1, eidx=i).
// Pairs sorted by i; contiguous even chunks per wave; epilogue flag at i-change
// or chunk end (partial epilogues exact: out is linear in V).
// entry = p | (jl<<9) | (eidx<<13) | (eflag<<18) | (eglob<<19)
struct Tab { int ent[8][40]; int c1[8]; int c2[8]; };
constexpr Tab build_tab() {
    Tab t{};
    int list[210][3] = {};
    int n = 0;
    for (int i = 0; i < 12; ++i)
        for (int j = i + 1; j < 12; ++j) {
            list[n][0] = 23 * i - i * (i - 1) / 2 + (j - i - 1);
            list[n][1] = j; list[n][2] = i; ++n;        // 66
        }
    {
        const int cnts[8] = {10, 8, 8, 8, 8, 8, 8, 8};
        int pos = 0;
        for (int w = 0; w < 8; ++w) {
            t.c1[w] = cnts[w];
            for (int k = 0; k < cnts[w]; ++k, ++pos) {
                int flag = (k == cnts[w] - 1) || (list[pos + 1][2] != list[pos][2]);
                t.ent[w][k] = list[pos][0] | (list[pos][1] << 9)
                            | (list[pos][2] << 13) | (flag << 18);
            }
        }
    }
    n = 0;
    for (int i = 0; i < 23; ++i) {
        int j0 = (i < 12) ? 12 : i + 1;
        for (int j = j0; j < 24; ++j) {
            list[n][0] = 23 * i - i * (i - 1) / 2 + (j - i - 1);
            list[n][1] = j - 12; list[n][2] = i; ++n;   // 210
        }
    }
    {
        const int cnts[8] = {26, 26, 26, 26, 26, 26, 26, 28};
        int pos = 0;
        for (int w = 0; w < 8; ++w) {
            t.c2[w] = cnts[w];
            for (int k = 0; k < cnts[w]; ++k, ++pos) {
                int flag = (k == cnts[w] - 1) || (list[pos + 1][2] != list[pos][2]);
                int i = list[pos][2];
                int eglob = (i < 12) ? 1 : 0;
                int eidx  = (i < 12) ? i : (i - 12);
                t.ent[w][t.c1[w] + k] = list[pos][0] | (list[pos][1] << 9)
                                      | (eidx << 13) | (flag << 18) | (eglob << 19);
            }
        }
    }
    return t;
}
__device__ __constant__ Tab gtab = build_tab();

// ---- prepass: W fp32 -> bf16 A-fragments, pair-major chunk layout ----------
// chunk(p, u) u=ks*2+m at afrag[((p*8+u)*64 + lane)*8]:
//   elem i = W[p][m*32 + (lane&31)][ks*16 + (lane>>5)*8 + i]
__global__ __launch_bounds__(256) void wprep(const float* __restrict__ W,
                                             unsigned short* __restrict__ afrag) {
    __shared__ __align__(16) unsigned short wlds[64 * 72];
    int p = blockIdx.x, t = threadIdx.x;
    const float4* src = (const float4*)(W + (size_t)p * 4096);
    #pragma unroll
    for (int c = 0; c < 4; ++c) {
        int i = t + c * 256;
        float4 v = src[i];
        int d = i >> 4;
        int e = (i & 15) * 4;
        ushort4 h; h.x=f2bf(v.x); h.y=f2bf(v.y); h.z=f2bf(v.z); h.w=f2bf(v.w);
        *(ushort4*)(&wlds[d * 72 + e]) = h;
    }
    __syncthreads();
    #pragma unroll
    for (int c = 0; c < 2; ++c) {
        int sl = t + c * 256;
        int u = sl >> 6, lane = sl & 63;
        int ks = u >> 1, m = u & 1;
        int d = m * 32 + (lane & 31);
        int e = ks * 16 + (lane >> 5) * 8;
        bf16x8 v = *(const bf16x8*)(&wlds[d * 72 + e]);
        *(bf16x8*)(afrag + ((size_t)(p * 8 + u) * 64 + lane) * 8) = v;
    }
}

// ---- macros: 4-chunk refills, named vars only (register-resident) ----------
// HALF in {0,1}: chunk group u = HALF*4 .. HALF*4+3
#define LDA4(P_, HALF_, A0,A1,A2,A3) do {                                      \
    const bf16x8* ap_ = afr + (size_t)(P_) * 512 + (HALF_) * 256 + lane;       \
    A0 = ap_[0]; A1 = ap_[64]; A2 = ap_[128]; A3 = ap_[192]; } while (0)

// half-step: 2 k-steps (4 B-frag LDS reads), 8 MFMAs, refill from pair NP_
// (2 pairs ahead -> load->use distance ~2 pairs, covers L2 latency)
#define HSTEP(E_, NP_, HALF_, A0,A1,A2,A3) do {                                \
    int jb_ = ((E_ >> 9) & 15) * 64 + q8 + (HALF_) * 32;                       \
    const unsigned short* b0p_ = xr0 + jb_;                                    \
    const unsigned short* b1p_ = xr1 + jb_;                                    \
    bf16x8 b00_ = *(const bf16x8*)(b0p_);                                      \
    bf16x8 b01_ = *(const bf16x8*)(b0p_ + 16);                                 \
    bf16x8 b10_ = *(const bf16x8*)(b1p_);                                      \
    bf16x8 b11_ = *(const bf16x8*)(b1p_ + 16);                                 \
    a00 = __builtin_amdgcn_mfma_f32_32x32x16_bf16(A0, b00_, a00, 0, 0, 0);     \
    a01 = __builtin_amdgcn_mfma_f32_32x32x16_bf16(A1, b00_, a01, 0, 0, 0);     \
    a10 = __builtin_amdgcn_mfma_f32_32x32x16_bf16(A0, b10_, a10, 0, 0, 0);     \
    a11 = __builtin_amdgcn_mfma_f32_32x32x16_bf16(A1, b10_, a11, 0, 0, 0);     \
    a00 = __builtin_amdgcn_mfma_f32_32x32x16_bf16(A2, b01_, a00, 0, 0, 0);     \
    a01 = __builtin_amdgcn_mfma_f32_32x32x16_bf16(A3, b01_, a01, 0, 0, 0);     \
    a10 = __builtin_amdgcn_mfma_f32_32x32x16_bf16(A2, b11_, a10, 0, 0, 0);     \
    a11 = __builtin_amdgcn_mfma_f32_32x32x16_bf16(A3, b11_, a11, 0, 0, 0);     \
    LDA4(NP_, HALF_, A0,A1,A2,A3); } while (0)

// ---- main kernel -----------------------------------------------------------
__global__ __launch_bounds__(NTH, 2) void fmfm_main(const float* __restrict__ x,
                                                    const unsigned short* __restrict__ afrag,
                                                    float* __restrict__ out) {
    __shared__ __align__(16) unsigned short xs[BT * ROWP];   // 99,328 B
    __shared__ float t_red[BT];
    const int tid = threadIdx.x;
    const int btile = blockIdx.x;
    const int lane = tid & 63;
    const int wv = __builtin_amdgcn_readfirstlane(tid >> 6);
    const int bcol = lane & 31;
    const int q = lane >> 5;
    const int q8 = q * 8, q4 = q * 4;

    if (tid < BT) t_red[tid] = 0.0f;

    const bf16x8* afr = (const bf16x8*)afrag;
    const float* xg  = x + (size_t)btile * BT * 1536;
    const float* xe0 = xg + (size_t)bcol * 1536 + q4;        // global epi, n=0 row
    const float* xe1 = xe0 + (size_t)32 * 1536;              // n=1 row
    const unsigned short* xr0 = xs + bcol * ROWP;
    const unsigned short* xr1 = xs + (bcol + 32) * ROWP;

    float tacc0 = 0.f, tacc1 = 0.f;
    f32x16 a00, a01, a10, a11;           // acc[n][m]
    auto zacc = [&]() {
        #pragma unroll
        for (int k = 0; k < 16; ++k) { a00[k]=0.f; a01[k]=0.f; a10[k]=0.f; a11[k]=0.f; }
    };
    zacc();

    // epilogue from LDS bf16 (i-field resident in current phase)
    auto epi_lds = [&](int fl) {
        const unsigned short* e0 = xr0 + fl * 64 + q4;
        const unsigned short* e1 = xr1 + fl * 64 + q4;
        #pragma unroll
        for (int g = 0; g < 4; ++g) {
            ushort4 u0 = *(const ushort4*)(e0 + 8 * g);
            tacc0 += a00[4*g+0]*bf2f(u0.x) + a00[4*g+1]*bf2f(u0.y)
                   + a00[4*g+2]*bf2f(u0.z) + a00[4*g+3]*bf2f(u0.w);
            u0 = *(const ushort4*)(e0 + 32 + 8 * g);
            tacc0 += a01[4*g+0]*bf2f(u0.x) + a01[4*g+1]*bf2f(u0.y)
                   + a01[4*g+2]*bf2f(u0.z) + a01[4*g+3]*bf2f(u0.w);
            u0 = *(const ushort4*)(e1 + 8 * g);
            tacc1 += a10[4*g+0]*bf2f(u0.x) + a10[4*g+1]*bf2f(u0.y)
                   + a10[4*g+2]*bf2f(u0.z) + a10[4*g+3]*bf2f(u0.w);
            u0 = *(const ushort4*)(e1 + 32 + 8 * g);
            tacc1 += a11[4*g+0]*bf2f(u0.x) + a11[4*g+1]*bf2f(u0.y)
                   + a11[4*g+2]*bf2f(u0.z) + a11[4*g+3]*bf2f(u0.w);
        }
    };
    // epilogue from global fp32 (phase-2 cross pairs, i<12)
    auto epi_glb = [&](int fi) {
        const float* e0 = xe0 + fi * 64;
        const float* e1 = xe1 + fi * 64;
        #pragma unroll
        for (int g = 0; g < 4; ++g) {
            float4 v = *(const float4*)(e0 + 8 * g);
            tacc0 += a00[4*g+0]*v.x + a00[4*g+1]*v.y + a00[4*g+2]*v.z + a00[4*g+3]*v.w;
            v = *(const float4*)(e0 + 32 + 8 * g);
            tacc0 += a01[4*g+0]*v.x + a01[4*g+1]*v.y + a01[4*g+2]*v.z + a01[4*g+3]*v.w;
            v = *(const float4*)(e1 + 8 * g);
            tacc1 += a10[4*g+0]*v.x + a10[4*g+1]*v.y + a10[4*g+2]*v.z + a10[4*g+3]*v.w;
            v = *(const float4*)(e1 + 32 + 8 * g);
            tacc1 += a11[4*g+0]*v.x + a11[4*g+1]*v.y + a11[4*g+2]*v.z + a11[4*g+3]*v.w;
        }
    };

    bf16x8 A0,A1,A2,A3,A4,A5,A6,A7;      // pair s   (named: register-resident)
    bf16x8 B0,B1,B2,B3,B4,B5,B6,B7;      // pair s+1

    #pragma unroll 1
    for (int ph = 0; ph < 2; ++ph) {
        int base = ph ? gtab.c1[wv] : 0;
        int cnt  = ph ? gtab.c2[wv] : gtab.c1[wv];
        int end  = base + cnt;
        // prefetch first two pairs' W BEFORE staging: loads fly during the stage
        int p0 = gtab.ent[wv][base] & 511;
        int p1 = gtab.ent[wv][base + 1] & 511;
        LDA4(p0, 0, A0,A1,A2,A3);
        LDA4(p0, 1, A4,A5,A6,A7);
        LDA4(p1, 0, B0,B1,B2,B3);
        LDA4(p1, 1, B4,B5,B6,B7);
        __syncthreads();                 // protect LDS from previous phase readers
        // stage field-half ph: 64 rows x 3KB, fully contiguous reads
        const float* src = xg + ph * 768;
        #pragma unroll 8
        for (int c = 0; c < 24; ++c) {
            int idx = tid + c * NTH;     // 0..12287
            int row = idx / 192;
            int c4  = idx - row * 192;
            float4 v = *(const float4*)(src + (size_t)row * 1536 + c4 * 4);
            ushort4 h; h.x=f2bf(v.x); h.y=f2bf(v.y); h.z=f2bf(v.z); h.w=f2bf(v.w);
            *(ushort4*)(&xs[row * ROWP + c4 * 4]) = h;
        }
        __syncthreads();
        #pragma unroll 1
        for (int s = base; s < end; s += 2) {        // cnt always even
            int e0 = gtab.ent[wv][s];
            int e1 = gtab.ent[wv][s + 1];
            int np0 = (s + 2 < end) ? (gtab.ent[wv][s + 2] & 511) : (e0 & 511);
            int np1 = (s + 3 < end) ? (gtab.ent[wv][s + 3] & 511) : (e1 & 511);
            HSTEP(e0, np0, 0, A0,A1,A2,A3);          // use pair s, refill s+2
            HSTEP(e0, np0, 1, A4,A5,A6,A7);
            if (e0 & (1 << 18)) {                    // wave-uniform epilogue
                int fx = (e0 >> 13) & 31;
                if (e0 & (1 << 19)) epi_glb(fx); else epi_lds(fx);
                zacc();
            }
            HSTEP(e1, np1, 0, B0,B1,B2,B3);          // use pair s+1, refill s+3
            HSTEP(e1, np1, 1, B4,B5,B6,B7);
            if (e1 & (1 << 18)) {
                int fx = (e1 >> 13) & 31;
                if (e1 & (1 << 19)) epi_glb(fx); else epi_lds(fx);
                zacc();
            }
        }
    }

    atomicAdd(&t_red[bcol],      tacc0);
    atomicAdd(&t_red[bcol + 32], tacc1);
    __syncthreads();
    if (tid < BT) out[(size_t)btile * BT + tid] = t_red[tid];
}

extern "C" void kernel_launch(void* const* d_in, const int* in_sizes, int n_in,
                              void* d_out, int out_size, void* d_ws, size_t ws_size,
                              hipStream_t stream) {
    const float* x = (const float*)d_in[0];
    const float* W = (const float*)d_in[1];
    float* out = (float*)d_out;
    unsigned short* afrag = (unsigned short*)d_ws;   // 2.26 MB scratch
    wprep<<<P_NUM, 256, 0, stream>>>(W, afrag);
    fmfm_main<<<B_TOT / BT, NTH, 0, stream>>>(x, afrag, out);
}

// Round 8
// 189.988 us; speedup vs baseline: 1.1972x; 1.0104x over previous
//
#include <hip/hip_runtime.h>
#include <stdint.h>

#define B_TOT 16384
#define F_NUM 24
#define P_NUM 276
#define BT    32          // b-rows per block (1 MFMA n-tile)
#define NTH   1024        // 16 waves -> 4 waves/SIMD
#define ROWP  1544        // shorts per LDS row: 24*64 + 8 pad

typedef float f32x16 __attribute__((ext_vector_type(16)));
typedef short bf16x8 __attribute__((ext_vector_type(8)));

__device__ inline unsigned short f2bf(float f) {
    unsigned u = __float_as_uint(f);
    u += 0x7fffu + ((u >> 16) & 1u);      // round-to-nearest-even
    return (unsigned short)(u >> 16);
}
__device__ inline float bf2f(unsigned short h) {
    return __uint_as_float(((unsigned)h) << 16);
}

// ---- pair schedule: 276 pairs (i-major) split into 16 contiguous chunks ----
// sizes {18 x4, 17 x12}; epilogue flag at i-change or chunk end (partial
// epilogues are exact: out is linear in V).  All epilogues read LDS (full
// 24-field tile resident -> no global gathers).
// entry = p | (j<<9) | (i<<14) | (flag<<19)
struct Tab { int ent[16][18]; int cnt[16]; };
constexpr Tab build_tab() {
    Tab t{};
    int ii[276] = {}, jj[276] = {};
    int n = 0;
    for (int i = 0; i < 24; ++i)
        for (int j = i + 1; j < 24; ++j) { ii[n] = i; jj[n] = j; ++n; }
    int pos = 0;
    for (int w = 0; w < 16; ++w) {
        int c = (w < 4) ? 18 : 17;       // 4*18 + 12*17 = 276
        t.cnt[w] = c;
        for (int k = 0; k < c; ++k, ++pos) {
            int flag = (k == c - 1) || (ii[pos + 1] != ii[pos]);
            t.ent[w][k] = pos | (jj[pos] << 9) | (ii[pos] << 14) | (flag << 19);
        }
    }
    return t;
}
__device__ __constant__ Tab gtab = build_tab();

// ---- prepass: W fp32 -> bf16 A-fragments, pair-major chunk layout ----------
// chunk(p, u) u=ks*2+m at afrag[((p*8+u)*64 + lane)*8]:
//   elem i = W[p][m*32 + (lane&31)][ks*16 + (lane>>5)*8 + i]
__global__ __launch_bounds__(256) void wprep(const float* __restrict__ W,
                                             unsigned short* __restrict__ afrag) {
    __shared__ __align__(16) unsigned short wlds[64 * 72];
    int p = blockIdx.x, t = threadIdx.x;
    const float4* src = (const float4*)(W + (size_t)p * 4096);
    #pragma unroll
    for (int c = 0; c < 4; ++c) {
        int i = t + c * 256;
        float4 v = src[i];
        int d = i >> 4;
        int e = (i & 15) * 4;
        ushort4 h; h.x=f2bf(v.x); h.y=f2bf(v.y); h.z=f2bf(v.z); h.w=f2bf(v.w);
        *(ushort4*)(&wlds[d * 72 + e]) = h;
    }
    __syncthreads();
    #pragma unroll
    for (int c = 0; c < 2; ++c) {
        int sl = t + c * 256;
        int u = sl >> 6, lane = sl & 63;
        int ks = u >> 1, m = u & 1;
        int d = m * 32 + (lane & 31);
        int e = ks * 16 + (lane >> 5) * 8;
        bf16x8 v = *(const bf16x8*)(&wlds[d * 72 + e]);
        *(bf16x8*)(afrag + ((size_t)(p * 8 + u) * 64 + lane) * 8) = v;
    }
}

// ---- macros: 4-chunk W buffers, named vars only (register-resident) --------
// HALF in {0,1}: chunk group u = HALF*4 .. HALF*4+3  (= ks{2H,2H+1} x m{0,1})
#define LDA4(P_, HALF_, A0,A1,A2,A3) do {                                      \
    const bf16x8* ap_ = afr + (size_t)(P_) * 512 + (HALF_) * 256 + lane;       \
    A0 = ap_[0]; A1 = ap_[64]; A2 = ap_[128]; A3 = ap_[192]; } while (0)

// half-step: 2 k-steps (2 b128 LDS reads), 4 MFMAs (2 m-chains), refill from
// pair NP_ (next pair -> load->use distance ~1 pair, hidden by 4 waves/SIMD)
#define HSTEP(E_, NP_, HALF_, A0,A1,A2,A3) do {                                \
    int jb_ = ((E_ >> 9) & 31) * 64 + q8 + (HALF_) * 32;                       \
    const unsigned short* bp_ = xrow + jb_;                                    \
    bf16x8 bt0_ = *(const bf16x8*)(bp_);                                       \
    bf16x8 bt1_ = *(const bf16x8*)(bp_ + 16);                                  \
    a0 = __builtin_amdgcn_mfma_f32_32x32x16_bf16(A0, bt0_, a0, 0, 0, 0);       \
    a1 = __builtin_amdgcn_mfma_f32_32x32x16_bf16(A1, bt0_, a1, 0, 0, 0);       \
    a0 = __builtin_amdgcn_mfma_f32_32x32x16_bf16(A2, bt1_, a0, 0, 0, 0);       \
    a1 = __builtin_amdgcn_mfma_f32_32x32x16_bf16(A3, bt1_, a1, 0, 0, 0);       \
    LDA4(NP_, HALF_, A0,A1,A2,A3); } while (0)

// ---- main kernel -----------------------------------------------------------
__global__ __launch_bounds__(NTH, 4) void fmfm_main(const float* __restrict__ x,
                                                    const unsigned short* __restrict__ afrag,
                                                    float* __restrict__ out) {
    __shared__ __align__(16) unsigned short xs[BT * ROWP];   // 98,816 B
    __shared__ float t_red[BT];
    const int tid = threadIdx.x;
    const int btile = blockIdx.x;
    const int lane = tid & 63;
    const int wv = __builtin_amdgcn_readfirstlane(tid >> 6);   // 0..15
    const int bcol = lane & 31;
    const int q = lane >> 5;
    const int q8 = q * 8, q4 = q * 4;

    if (tid < BT) t_red[tid] = 0.0f;

    const bf16x8* afr = (const bf16x8*)afrag;
    const unsigned short* xrow = xs + bcol * ROWP;

    float tacc = 0.f;
    f32x16 a0, a1;                        // acc[m]
    #pragma unroll
    for (int k = 0; k < 16; ++k) { a0[k] = 0.f; a1[k] = 0.f; }

    bf16x8 A0,A1,A2,A3;                  // W buffer, ks{0,1} of current pair
    bf16x8 B0,B1,B2,B3;                  // W buffer, ks{2,3} of current pair

    const int cnt = gtab.cnt[wv];
    // prefetch first pair's W BEFORE staging: loads fly during the stage
    {
        int p0 = gtab.ent[wv][0] & 511;
        LDA4(p0, 0, A0,A1,A2,A3);
        LDA4(p0, 1, B0,B1,B2,B3);
    }

    // stage full tile: 32 rows x 6KB fp32 -> bf16 LDS, fully contiguous reads
    const float* xg = x + (size_t)btile * BT * 1536;
    #pragma unroll 4
    for (int c = 0; c < 12; ++c) {
        int idx = tid + c * NTH;         // 0..12287 float4 index
        int row = idx / 384;
        int c4  = idx - row * 384;
        float4 v = *(const float4*)(xg + (size_t)row * 1536 + c4 * 4);
        ushort4 h; h.x=f2bf(v.x); h.y=f2bf(v.y); h.z=f2bf(v.z); h.w=f2bf(v.w);
        *(ushort4*)(&xs[row * ROWP + c4 * 4]) = h;
    }
    __syncthreads();

    #pragma unroll 1
    for (int s = 0; s < cnt; ++s) {
        int e  = gtab.ent[wv][s];
        int sn = (s + 1 < cnt) ? s + 1 : s;
        int np = gtab.ent[wv][sn] & 511;
        HSTEP(e, np, 0, A0,A1,A2,A3);    // ks 0,1 + refill A(next pair)
        HSTEP(e, np, 1, B0,B1,B2,B3);    // ks 2,3 + refill B(next pair)
        if (e & (1 << 19)) {             // wave-uniform epilogue, all from LDS
            int fi = (e >> 14) & 31;
            const unsigned short* ep = xrow + fi * 64 + q4;
            #pragma unroll
            for (int g = 0; g < 4; ++g) {
                ushort4 u0 = *(const ushort4*)(ep + 8 * g);          // m=0
                tacc += a0[4*g+0]*bf2f(u0.x) + a0[4*g+1]*bf2f(u0.y)
                      + a0[4*g+2]*bf2f(u0.z) + a0[4*g+3]*bf2f(u0.w);
                u0 = *(const ushort4*)(ep + 32 + 8 * g);             // m=1
                tacc += a1[4*g+0]*bf2f(u0.x) + a1[4*g+1]*bf2f(u0.y)
                      + a1[4*g+2]*bf2f(u0.z) + a1[4*g+3]*bf2f(u0.w);
            }
            #pragma unroll
            for (int k = 0; k < 16; ++k) { a0[k] = 0.f; a1[k] = 0.f; }
        }
    }

    atomicAdd(&t_red[bcol], tacc);
    __syncthreads();
    if (tid < BT) out[(size_t)btile * BT + tid] = t_red[tid];
}

extern "C" void kernel_launch(void* const* d_in, const int* in_sizes, int n_in,
                              void* d_out, int out_size, void* d_ws, size_t ws_size,
                              hipStream_t stream) {
    const float* x = (const float*)d_in[0];
    const float* W = (const float*)d_in[1];
    float* out = (float*)d_out;
    unsigned short* afrag = (unsigned short*)d_ws;   // 2.26 MB scratch
    wprep<<<P_NUM, 256, 0, stream>>>(W, afrag);
    fmfm_main<<<B_TOT / BT, NTH, 0, stream>>>(x, afrag, out);
}